// Round 8
// baseline (198.730 us; speedup 1.0000x reference)
//
#include <hip/hip_runtime.h>

#define NCH 23
#define STEP_ELEMS 2048   // elements per block-step (8 KB x + 8 KB labels)
#define XCHUNK 1024       // elements per DMA call (256 thr x 16 B)

typedef float fvec4 __attribute__((ext_vector_type(4)));
typedef int   ivec4 __attribute__((ext_vector_type(4)));

// Class frequencies W from the reference.
constexpr float c_W[NCH] = {
    0.0012597430655963838f, 0.0004919313290455535f, 0.0021106513104319356f,
    0.0007678117365508301f, 0.004719881670572202f,  0.000372272357115554f,
    0.029090425620315438f,  0.010056339432617042f,  0.0034817436971298467f,
    0.0003057951504877765f, 0.003995280118329428f,  8.808229878180519e-05f,
    0.012070598793438699f,  0.016788818533845208f,  0.0017832510677901316f,
    0.0008758371973209686f, 0.0005933090691529143f, 0.0031992155689617922f,
    0.003212511010287348f,  0.0016685778863572154f, 0.0009356666832859684f,
    0.0010985358395240233f, 0.00103372056306194f
};
constexpr float NEG_LN2 = -0.69314718055994530942f;

// Combined weight table pre-multiplied by -ln2: w[c] for target==0, w[23+c]
// for target==1. fp32 op order matches reference.
struct Tabs { float w[2 * NCH]; };
constexpr Tabs make_tabs() {
    Tabs t{};
    for (int c = 0; c < NCH; ++c) {
        float w0 = 1.0f / (c_W[c] + 1.0f);   // _WEIGHT_0
        float w1 = 1.0f - w0;                // _WEIGHT_1
        t.w[c]       = (1.0f / w0) * NEG_LN2;
        t.w[NCH + c] = (1.0f / w1) * NEG_LN2;
    }
    return t;
}
__constant__ Tabs d_tabs = make_tabs();

__device__ __forceinline__ unsigned wrap23(unsigned c) {
    return c >= NCH ? c - NCH : c;
}

__device__ __forceinline__ void elem(float xx, int lab, unsigned c,
                                     const float* s_wt, float& acc) {
    bool t  = lab > 0;
    float v = t ? xx : 1.0f - xx;
    float w = s_wt[c + (t ? NCH : 0u)];
    acc = __builtin_fmaf(w, __log2f(v), acc);     // wn * log2(v), wn = w * -ln2
}

// Async global->LDS DMA, 16 B per lane. LDS dest is wave-uniform base +
// lane*16; our layout is exactly lane-order contiguous, as required (m104).
__device__ __forceinline__ void gld_lds16(const void* g, void* l) {
    __builtin_amdgcn_global_load_lds(
        (const __attribute__((address_space(1))) void*)g,
        (__attribute__((address_space(3))) void*)l, 16, 0, 0);
}

__global__ __launch_bounds__(256) void bce_reduce_kernel(
        const float* __restrict__ x, const int* __restrict__ labels,
        double* __restrict__ partial, unsigned n) {
    __shared__ float s_wt[2 * NCH];
    __shared__ float sx[STEP_ELEMS];
    __shared__ int   sl[STEP_ELEMS];

    const unsigned tid = threadIdx.x;
    if (tid < 2 * NCH) s_wt[tid] = d_tabs.w[tid];

    const unsigned nsteps = n / STEP_ELEMS;
    float acc0 = 0.0f, acc1 = 0.0f;

    for (unsigned g = blockIdx.x; g < nsteps; g += gridDim.x) {
        const unsigned ebase = g * STEP_ELEMS;
        // Stage 16 KB via the LDS-DMA path (4 wave-level dwordx4 DMAs/wave).
        gld_lds16(x + ebase + tid * 4u,               sx + tid * 4u);
        gld_lds16(x + ebase + XCHUNK + tid * 4u,      sx + XCHUNK + tid * 4u);
        gld_lds16(labels + ebase + tid * 4u,          sl + tid * 4u);
        gld_lds16(labels + ebase + XCHUNK + tid * 4u, sl + XCHUNK + tid * 4u);
        __syncthreads();  // vmcnt(0) drain: DMA complete (also covers s_wt)

        fvec4 xv0 = *(const fvec4*)(sx + tid * 4u);
        ivec4 lv0 = *(const ivec4*)(sl + tid * 4u);
        fvec4 xv1 = *(const fvec4*)(sx + XCHUNK + tid * 4u);
        ivec4 lv1 = *(const ivec4*)(sl + XCHUNK + tid * 4u);

        unsigned c0 = (ebase + tid * 4u) % NCH;   // one mod per step
        unsigned c  = c0;
        elem(xv0.x, lv0.x, c, s_wt, acc0); c = wrap23(c + 1);
        elem(xv0.y, lv0.y, c, s_wt, acc0); c = wrap23(c + 1);
        elem(xv0.z, lv0.z, c, s_wt, acc0); c = wrap23(c + 1);
        elem(xv0.w, lv0.w, c, s_wt, acc0);
        c = wrap23(c0 + 12u);                     // +1024 mod 23 = +12
        elem(xv1.x, lv1.x, c, s_wt, acc1); c = wrap23(c + 1);
        elem(xv1.y, lv1.y, c, s_wt, acc1); c = wrap23(c + 1);
        elem(xv1.z, lv1.z, c, s_wt, acc1); c = wrap23(c + 1);
        elem(xv1.w, lv1.w, c, s_wt, acc1);

        __syncthreads();  // protect LDS from next step's DMA
    }

    // Tail: elements [nsteps*2048, n) via direct loads (960 elems for 23e6).
    const unsigned gtid     = blockIdx.x * blockDim.x + tid;
    const unsigned nthreads = gridDim.x * blockDim.x;
    for (unsigned i = nsteps * STEP_ELEMS + gtid; i < n; i += nthreads) {
        elem(x[i], labels[i], i % NCH, s_wt, acc0);
    }

    float acc = acc0 + acc1;

    // Wave (64-lane) shuffle reduce, then LDS across the 4 waves.
    #pragma unroll
    for (int off = 32; off > 0; off >>= 1) acc += __shfl_down(acc, off, 64);
    __shared__ float s_part[4];
    const int wave = threadIdx.x >> 6;
    if ((threadIdx.x & 63) == 0) s_part[wave] = acc;
    __syncthreads();
    if (threadIdx.x == 0) {
        float s = s_part[0] + s_part[1] + s_part[2] + s_part[3];
        atomicAdd(partial, (double)s);
    }
}

__global__ void bce_finalize_kernel(const double* __restrict__ partial,
                                    float* __restrict__ out, unsigned n) {
    out[0] = (float)(partial[0] / (double)n);
}

extern "C" void kernel_launch(void* const* d_in, const int* in_sizes, int n_in,
                              void* d_out, int out_size, void* d_ws, size_t ws_size,
                              hipStream_t stream) {
    const float* x      = (const float*)d_in[0];
    const int*   labels = (const int*)d_in[1];
    float*       out    = (float*)d_out;
    double*      acc    = (double*)d_ws;
    unsigned n = (unsigned)in_sizes[0];  // B*C = 23,000,000

    (void)hipMemsetAsync(acc, 0, sizeof(double), stream);

    const int block = 256;
    const int grid  = 2048;  // 8 blocks/CU; DMA waits overlap across blocks
    bce_reduce_kernel<<<grid, block, 0, stream>>>(x, labels, acc, n);
    bce_finalize_kernel<<<1, 1, 0, stream>>>(acc, out, n);
}

// Round 9
// 193.381 us; speedup vs baseline: 1.0277x; 1.0277x over previous
//
#include <hip/hip_runtime.h>

#define NCH 23
#define U 8                 // vec4 loads per lane per wave-tile
#define TILE_V4 (64 * U)    // 512 vec4s per tile = 2048 elements

typedef float fvec4 __attribute__((ext_vector_type(4)));
typedef int   ivec4 __attribute__((ext_vector_type(4)));

// Class frequencies W from the reference.
constexpr float c_W[NCH] = {
    0.0012597430655963838f, 0.0004919313290455535f, 0.0021106513104319356f,
    0.0007678117365508301f, 0.004719881670572202f,  0.000372272357115554f,
    0.029090425620315438f,  0.010056339432617042f,  0.0034817436971298467f,
    0.0003057951504877765f, 0.003995280118329428f,  8.808229878180519e-05f,
    0.012070598793438699f,  0.016788818533845208f,  0.0017832510677901316f,
    0.0008758371973209686f, 0.0005933090691529143f, 0.0031992155689617922f,
    0.003212511010287348f,  0.0016685778863572154f, 0.0009356666832859684f,
    0.0010985358395240233f, 0.00103372056306194f
};
constexpr float NEG_LN2 = -0.69314718055994530942f;

// Combined weight table pre-multiplied by -ln2: w[c] for target==0, w[23+c]
// for target==1. fp32 op order matches reference.
struct Tabs { float w[2 * NCH]; };
constexpr Tabs make_tabs() {
    Tabs t{};
    for (int c = 0; c < NCH; ++c) {
        float w0 = 1.0f / (c_W[c] + 1.0f);   // _WEIGHT_0
        float w1 = 1.0f - w0;                // _WEIGHT_1
        t.w[c]       = (1.0f / w0) * NEG_LN2;
        t.w[NCH + c] = (1.0f / w1) * NEG_LN2;
    }
    return t;
}
__constant__ Tabs d_tabs = make_tabs();

__device__ __forceinline__ unsigned wrap23(unsigned c) {
    return c >= NCH ? c - NCH : c;
}

__device__ __forceinline__ void elem(float xx, int lab, unsigned c,
                                     const float* s_wt, float& acc) {
    bool t  = lab > 0;
    float v = t ? xx : 1.0f - xx;
    float w = s_wt[c + (t ? NCH : 0u)];           // one ds_read_b32
    acc = __builtin_fmaf(w, __log2f(v), acc);     // wn * log2(v), wn = w * -ln2
}

__global__ __launch_bounds__(256) void bce_reduce_kernel(
        const fvec4* __restrict__ x4, const ivec4* __restrict__ l4,
        double* __restrict__ partial, unsigned n4 /* count of vec4s */) {
    __shared__ float s_wt[2 * NCH];
    if (threadIdx.x < 2 * NCH) s_wt[threadIdx.x] = d_tabs.w[threadIdx.x];
    __syncthreads();

    const unsigned gtid     = blockIdx.x * blockDim.x + threadIdx.x;
    const unsigned nthreads = gridDim.x * blockDim.x;
    const unsigned lane     = threadIdx.x & 63u;
    const unsigned wid      = gtid >> 6;
    const unsigned nwaves   = nthreads >> 6;
    const unsigned ntiles   = n4 / TILE_V4;

    float acc0 = 0.0f, acc1 = 0.0f;

    for (unsigned T = wid; T < ntiles; T += nwaves) {
        const fvec4* px = x4 + (size_t)T * TILE_V4 + lane;
        const ivec4* pl = l4 + (size_t)T * TILE_V4 + lane;
        fvec4 xv[U];
        ivec4 lv[U];
        // 2U = 16 independent, wave-coalesced, nontemporal 16B loads.
        #pragma unroll
        for (int j = 0; j < U; ++j)
            xv[j] = __builtin_nontemporal_load(px + 64u * j);
        #pragma unroll
        for (int j = 0; j < U; ++j)
            lv[j] = __builtin_nontemporal_load(pl + 64u * j);
        // Pin the load group ABOVE the compute group: forbid the scheduler
        // from sinking loads to their uses (R3/R4 showed it does: VGPR=32).
        __builtin_amdgcn_sched_barrier(0);

        // channel of elem0 of load j: (4*(T*512 + 64j + lane)) % 23
        //   = (T + 3j + 4*lane) % 23  (2048 = 89*23+1, 256 = 11*23+3).
        const unsigned cb = (T + 4u * lane) % NCH;
        #pragma unroll
        for (int j = 0; j < U; ++j) {
            unsigned c = wrap23(cb + (3u * j) % NCH);  // (3j)%23 compile-time
            float& a = (j & 1) ? acc1 : acc0;
            elem(xv[j].x, lv[j].x, c, s_wt, a); c = wrap23(c + 1);
            elem(xv[j].y, lv[j].y, c, s_wt, a); c = wrap23(c + 1);
            elem(xv[j].z, lv[j].z, c, s_wt, a); c = wrap23(c + 1);
            elem(xv[j].w, lv[j].w, c, s_wt, a);
        }
    }

    // Tail over leftover vec4s (n4 % 512).
    for (unsigned v = ntiles * TILE_V4 + gtid; v < n4; v += nthreads) {
        fvec4 xv = __builtin_nontemporal_load(x4 + v);
        ivec4 lv = __builtin_nontemporal_load(l4 + v);
        unsigned c = (4u * v) % NCH;
        elem(xv.x, lv.x, c, s_wt, acc0); c = wrap23(c + 1);
        elem(xv.y, lv.y, c, s_wt, acc0); c = wrap23(c + 1);
        elem(xv.z, lv.z, c, s_wt, acc0); c = wrap23(c + 1);
        elem(xv.w, lv.w, c, s_wt, acc0);
    }

    float acc = acc0 + acc1;

    // Wave (64-lane) shuffle reduce, then LDS across the 4 waves.
    #pragma unroll
    for (int off = 32; off > 0; off >>= 1) acc += __shfl_down(acc, off, 64);
    __shared__ float s_part[4];
    const int wave = threadIdx.x >> 6;
    if ((threadIdx.x & 63) == 0) s_part[wave] = acc;
    __syncthreads();
    if (threadIdx.x == 0) {
        float s = s_part[0] + s_part[1] + s_part[2] + s_part[3];
        atomicAdd(partial, (double)s);
    }
}

__global__ void bce_finalize_kernel(const double* __restrict__ partial,
                                    float* __restrict__ out, unsigned n) {
    out[0] = (float)(partial[0] / (double)n);
}

extern "C" void kernel_launch(void* const* d_in, const int* in_sizes, int n_in,
                              void* d_out, int out_size, void* d_ws, size_t ws_size,
                              hipStream_t stream) {
    const float* x      = (const float*)d_in[0];
    const int*   labels = (const int*)d_in[1];
    float*       out    = (float*)d_out;
    double*      acc    = (double*)d_ws;
    unsigned n  = (unsigned)in_sizes[0];  // B*C = 23,000,000 (divisible by 4)
    unsigned n4 = n >> 2;

    (void)hipMemsetAsync(acc, 0, sizeof(double), stream);

    const int block = 256;
    const int grid  = 2048;  // 8192 waves
    bce_reduce_kernel<<<grid, block, 0, stream>>>(
        (const fvec4*)x, (const ivec4*)labels, acc, n4);
    bce_finalize_kernel<<<1, 1, 0, stream>>>(acc, out, n);
}